// Round 1
// baseline (546.291 us; speedup 1.0000x reference)
//
#include <hip/hip_runtime.h>

#define B_ 8
#define C_ 64
#define N_ 4096
#define P_ 8

// ---------------------------------------------------------------------------
// Kernel A: 1x1-conv projections.
//   q[b,i,p] = sum_c wq[p,c]*query_x[b,c,i] + bq[p]   -> qws [B,N,8]
//   k[b,i,p] = sum_c wk[p,c]*ref_x[b,c,i]   + bk[p]   -> kws [B,N,8]
//   v[b,i,o] = sum_c wv[o,c]*ref_x[b,c,i]   + bv[o]   -> vws [B,N,64]
// One thread per (b,i). Weight reads are wave-uniform -> scalar loads.
// ---------------------------------------------------------------------------
__global__ __launch_bounds__(256) void proj_kernel(
    const float* __restrict__ qx, const float* __restrict__ rx,
    const float* __restrict__ wq, const float* __restrict__ bq,
    const float* __restrict__ wk, const float* __restrict__ bk,
    const float* __restrict__ wv, const float* __restrict__ bv,
    float* __restrict__ qws, float* __restrict__ kws, float* __restrict__ vws)
{
    const int gid = blockIdx.x * 256 + threadIdx.x;   // gid = b*N + i
    const int b   = gid >> 12;                        // / 4096
    const int i   = gid & (N_ - 1);

    const float* qxp = qx + (size_t)b * C_ * N_ + i;
    const float* rxp = rx + (size_t)b * C_ * N_ + i;

    float accq[P_], acck[P_], accv[C_];
#pragma unroll
    for (int p = 0; p < P_; ++p) { accq[p] = bq[p]; acck[p] = bk[p]; }
#pragma unroll
    for (int o = 0; o < C_; ++o) accv[o] = bv[o];

    for (int c = 0; c < C_; ++c) {
        const float xq = qxp[(size_t)c * N_];
        const float xr = rxp[(size_t)c * N_];
#pragma unroll
        for (int p = 0; p < P_; ++p) {
            accq[p] = fmaf(wq[p * C_ + c], xq, accq[p]);
            acck[p] = fmaf(wk[p * C_ + c], xr, acck[p]);
        }
#pragma unroll
        for (int o = 0; o < C_; ++o)
            accv[o] = fmaf(wv[o * C_ + c], xr, accv[o]);
    }

    // Stores: contiguous per thread, vectorized.
    float4* qdst = (float4*)(qws + (size_t)gid * P_);
    float4* kdst = (float4*)(kws + (size_t)gid * P_);
    qdst[0] = make_float4(accq[0], accq[1], accq[2], accq[3]);
    qdst[1] = make_float4(accq[4], accq[5], accq[6], accq[7]);
    kdst[0] = make_float4(acck[0], acck[1], acck[2], acck[3]);
    kdst[1] = make_float4(acck[4], acck[5], acck[6], acck[7]);
    float4* vdst = (float4*)(vws + (size_t)gid * C_);
#pragma unroll
    for (int o = 0; o < C_; o += 4)
        vdst[o >> 2] = make_float4(accv[o], accv[o + 1], accv[o + 2], accv[o + 3]);
}

// ---------------------------------------------------------------------------
// Kernel B: flash-style attention, fp32 vector.
// Block = (batch b, 32 j-rows). 256 threads = 32 groups of 8 lanes.
//   group jl handles row j = j0+jl; lane l owns v-channels [8l, 8l+8).
// Per 32-wide i-tile: stage q(32x8) + v(32x64) in LDS; each lane computes
// energies for i = r*8+l (r=0..3), w = exp(e) (no max-sub: |e| <~ 6, safe
// in fp32 and mathematically identical to softmax); PV loop broadcasts w
// within the 8-lane group via __shfl(width=8) and accumulates 8 channels.
// ---------------------------------------------------------------------------
__global__ __launch_bounds__(256) void attn_kernel(
    const float* __restrict__ qws, const float* __restrict__ kws,
    const float* __restrict__ vws, const float* __restrict__ qx,
    float* __restrict__ out)
{
    __shared__ float q_lds[32 * P_];    // 1 KB
    __shared__ float v_lds[32 * C_];    // 8 KB

    const int tid = threadIdx.x;
    const int b   = blockIdx.y;
    const int j0  = blockIdx.x * 32;
    const int jl  = tid >> 3;
    const int l   = tid & 7;
    const int j   = j0 + jl;
    const int c0  = l * 8;

    // Row's k vector (8 floats) in registers.
    float kj[8];
    {
        const float4* kp = (const float4*)(kws + ((size_t)b * N_ + j) * P_);
        float4 a = kp[0], c = kp[1];
        kj[0] = a.x; kj[1] = a.y; kj[2] = a.z; kj[3] = a.w;
        kj[4] = c.x; kj[5] = c.y; kj[6] = c.z; kj[7] = c.w;
    }

    float acc[8] = {0.f, 0.f, 0.f, 0.f, 0.f, 0.f, 0.f, 0.f};
    float lsum = 0.f;

    for (int i0 = 0; i0 < N_; i0 += 32) {
        __syncthreads();   // previous tile fully consumed before overwrite
        // stage q tile: 256 floats, 1/thread
        q_lds[tid] = qws[((size_t)b * N_ + i0) * P_ + tid];
        // stage v tile: 2048 floats, 8/thread (2x float4), fully coalesced
        {
            const float4* vsrc = (const float4*)(vws + ((size_t)b * N_ + i0) * C_) + tid * 2;
            float4 v0 = vsrc[0], v1 = vsrc[1];
            ((float4*)v_lds)[tid * 2]     = v0;
            ((float4*)v_lds)[tid * 2 + 1] = v1;
        }
        __syncthreads();

        // energies for this lane's i-subset
        float w[4];
#pragma unroll
        for (int r = 0; r < 4; ++r) {
            const float* qr = &q_lds[(r * 8 + l) * P_];
            float e = 0.f;
#pragma unroll
            for (int p = 0; p < P_; ++p) e = fmaf(kj[p], qr[p], e);
            w[r] = __expf(e);
        }

        // PV: broadcast w within 8-lane group, accumulate 8 channels
#pragma unroll
        for (int t = 0; t < 32; ++t) {
            const float wb = __shfl(w[t >> 3], t & 7, 8);
            lsum += wb;
            const float* vr = &v_lds[t * C_ + c0];
#pragma unroll
            for (int c = 0; c < 8; ++c) acc[c] = fmaf(wb, vr[c], acc[c]);
        }
    }

    const float inv = 1.0f / lsum;
    const float* xp = qx  + (size_t)b * C_ * N_ + (size_t)c0 * N_ + j;
    float*       op = out + (size_t)b * C_ * N_ + (size_t)c0 * N_ + j;
#pragma unroll
    for (int c = 0; c < 8; ++c)
        op[(size_t)c * N_] = xp[(size_t)c * N_] + acc[c] * inv;
}

extern "C" void kernel_launch(void* const* d_in, const int* in_sizes, int n_in,
                              void* d_out, int out_size, void* d_ws, size_t ws_size,
                              hipStream_t stream) {
    const float* qx = (const float*)d_in[0];
    const float* rx = (const float*)d_in[1];
    const float* wq = (const float*)d_in[2];
    const float* bq = (const float*)d_in[3];
    const float* wk = (const float*)d_in[4];
    const float* bk = (const float*)d_in[5];
    const float* wv = (const float*)d_in[6];
    const float* bv = (const float*)d_in[7];
    float* out = (float*)d_out;

    float* ws  = (float*)d_ws;
    float* qws = ws;                                   // B*N*8  = 1 MB
    float* kws = ws + (size_t)B_ * N_ * P_;            // B*N*8  = 1 MB
    float* vws = ws + (size_t)2 * B_ * N_ * P_;        // B*N*64 = 8 MB

    proj_kernel<<<dim3((B_ * N_) / 256), 256, 0, stream>>>(
        qx, rx, wq, bq, wk, bk, wv, bv, qws, kws, vws);

    attn_kernel<<<dim3(N_ / 32, B_), 256, 0, stream>>>(
        qws, kws, vws, qx, out);
}

// Round 2
// 156.282 us; speedup vs baseline: 3.4955x; 3.4955x over previous
//
#include <hip/hip_runtime.h>

#define B_ 8
#define C_ 64
#define N_ 4096
#define P_ 8

typedef __attribute__((ext_vector_type(8))) short bf16x8;
typedef __attribute__((ext_vector_type(4))) float f32x4;

static __device__ inline ushort f2bf(float x) {
    union { float f; unsigned u; } c; c.f = x;
    unsigned r = (c.u + 0x7FFFu + ((c.u >> 16) & 1u)) >> 16;   // RNE
    return (ushort)r;
}

static __device__ inline bf16x8 bzero() {
    bf16x8 v;
#pragma unroll
    for (int e = 0; e < 8; ++e) v[e] = 0;
    return v;
}

static __device__ inline int4 pack8(const ushort* s) {
    int4 r;
    r.x = (int)(s[0] | ((unsigned)s[1] << 16));
    r.y = (int)(s[2] | ((unsigned)s[3] << 16));
    r.z = (int)(s[4] | ((unsigned)s[5] << 16));
    r.w = (int)(s[6] | ((unsigned)s[7] << 16));
    return r;
}

// ---------------------------------------------------------------------------
// Kernel A: 1x1-conv projections -> bf16.
//   qb[b,i,p], kb[b,i,p]  (rows are ready-made MFMA fragments, K=8)
//   vb[b,i,c]             (row-major, transposed later)
// ---------------------------------------------------------------------------
__global__ __launch_bounds__(256) void proj_kernel(
    const float* __restrict__ qx, const float* __restrict__ rx,
    const float* __restrict__ wq, const float* __restrict__ bq,
    const float* __restrict__ wk, const float* __restrict__ bk,
    const float* __restrict__ wv, const float* __restrict__ bv,
    ushort* __restrict__ qb, ushort* __restrict__ kb, ushort* __restrict__ vb)
{
    const int gid = blockIdx.x * 256 + threadIdx.x;   // gid = b*N + i
    const int b   = gid >> 12;
    const int i   = gid & (N_ - 1);

    const float* qxp = qx + (size_t)b * C_ * N_ + i;
    const float* rxp = rx + (size_t)b * C_ * N_ + i;

    float accq[P_], acck[P_], accv[C_];
#pragma unroll
    for (int p = 0; p < P_; ++p) { accq[p] = bq[p]; acck[p] = bk[p]; }
#pragma unroll
    for (int o = 0; o < C_; ++o) accv[o] = bv[o];

    for (int c = 0; c < C_; ++c) {
        const float xq = qxp[(size_t)c * N_];
        const float xr = rxp[(size_t)c * N_];
#pragma unroll
        for (int p = 0; p < P_; ++p) {
            accq[p] = fmaf(wq[p * C_ + c], xq, accq[p]);
            acck[p] = fmaf(wk[p * C_ + c], xr, acck[p]);
        }
#pragma unroll
        for (int o = 0; o < C_; ++o)
            accv[o] = fmaf(wv[o * C_ + c], xr, accv[o]);
    }

    ushort q8[8], k8[8], v64[64];
#pragma unroll
    for (int p = 0; p < P_; ++p) { q8[p] = f2bf(accq[p]); k8[p] = f2bf(acck[p]); }
#pragma unroll
    for (int o = 0; o < C_; ++o) v64[o] = f2bf(accv[o]);

    *(int4*)(qb + (size_t)gid * 8) = pack8(q8);
    *(int4*)(kb + (size_t)gid * 8) = pack8(k8);
    int4* vd = (int4*)(vb + (size_t)gid * 64);
#pragma unroll
    for (int o = 0; o < 8; ++o) vd[o] = pack8(&v64[o * 8]);
}

// ---------------------------------------------------------------------------
// Kernel B: V transpose  vb[b,i,c] -> vt[b,c,i]  (bf16), 64x64 tiles via LDS.
// ---------------------------------------------------------------------------
__global__ __launch_bounds__(256) void transpose_v(
    const ushort* __restrict__ vb, ushort* __restrict__ vt)
{
    __shared__ ushort tile[64][72];   // +8 pad
    const int b  = blockIdx.y;
    const int i0 = blockIdx.x * 64;
    const int t  = threadIdx.x;

    {
        const int il = t >> 2, cc = (t & 3) * 16;
        const int4* src = (const int4*)(vb + ((size_t)b * N_ + i0 + il) * 64 + cc);
        *(int4*)&tile[il][cc]     = src[0];
        *(int4*)&tile[il][cc + 8] = src[1];
    }
    __syncthreads();
    {
        const int cl = t >> 2, ic = (t & 3) * 16;
        ushort ov[16];
#pragma unroll
        for (int m = 0; m < 16; ++m) ov[m] = tile[ic + m][cl];
        ushort* dst = vt + ((size_t)b * C_ + cl) * N_ + i0 + ic;
        *(int4*)dst       = pack8(&ov[0]);
        *(int4*)(dst + 8) = pack8(&ov[8]);
    }
}

// ---------------------------------------------------------------------------
// Kernel C: flash attention, bf16 MFMA (16x16x32).
// Block = (b, 64 j-rows) = 4 waves x 16 j. i-tiles of 32.
//  energy: A = K-rows (K-dim p padded 8->32), B = Q rows      -> 2 MFMA
//  P = exp(S) fp32 -> bf16 via per-wave LDS relayout          -> A-frag
//  PV:     A = P, B = V^T tile staged in LDS                  -> 4 MFMA
// No max-subtraction: |energy| <~ 4 (verified round 1).
// ---------------------------------------------------------------------------
__global__ __launch_bounds__(256) void attn_kernel(
    const ushort* __restrict__ qb, const ushort* __restrict__ kb,
    const ushort* __restrict__ vt, const float* __restrict__ qx,
    float* __restrict__ out)
{
    __shared__ ushort vt_lds[64 * 40];     // [c][40] bf16, 32 used + pad
    __shared__ ushort p_lds[4 * 16 * 40];  // per-wave [16][40]
    __shared__ float  o_lds[64 * 65];      // epilogue transpose

    const int tid = threadIdx.x;
    const int w   = tid >> 6;
    const int l   = tid & 63;
    const int cc  = l & 15;
    const int g   = l >> 4;
    const int b   = blockIdx.y;
    const int j0  = blockIdx.x * 64;
    const int jw  = j0 + w * 16;

    // K A-fragment (constant over i): lanes 0-15 hold k-row jw+l, rest zero (pad)
    bf16x8 ak = bzero();
    if (l < 16)
        ak = *(const bf16x8*)(kb + ((size_t)b * N_ + jw + l) * 8);

    f32x4 acc[4];
#pragma unroll
    for (int ct = 0; ct < 4; ++ct) acc[ct] = (f32x4){0.f, 0.f, 0.f, 0.f};
    f32x4 lsum = {0.f, 0.f, 0.f, 0.f};
    const f32x4 zero4 = {0.f, 0.f, 0.f, 0.f};

    // V staging addresses (block-wide): thread -> (c row, 8-elem chunk)
    const int sc  = tid >> 2;
    const int sch = (tid & 3) * 8;
    const ushort* vsrc = vt + ((size_t)b * C_ + sc) * N_ + sch;
    ushort* vdst = &vt_lds[sc * 40 + sch];
    ushort* pw   = &p_lds[w * 640];

    for (int i0 = 0; i0 < N_; i0 += 32) {
        // Q B-fragments (global; lanes 0-15 carry p=0..7, rest zero-pad)
        bf16x8 bq0 = bzero(), bq1 = bzero();
        if (l < 16) {
            bq0 = *(const bf16x8*)(qb + ((size_t)b * N_ + i0 + l) * 8);
            bq1 = *(const bf16x8*)(qb + ((size_t)b * N_ + i0 + 16 + l) * 8);
        }
        __syncthreads();                       // prev tile consumed
        *(int4*)vdst = *(const int4*)(vsrc + i0);
        __syncthreads();                       // tile ready

        // energy S[j, i] : rows jw+4g+r, cols i0+cc (+16)
        f32x4 e0 = __builtin_amdgcn_mfma_f32_16x16x32_bf16(ak, bq0, zero4, 0, 0, 0);
        f32x4 e1 = __builtin_amdgcn_mfma_f32_16x16x32_bf16(ak, bq1, zero4, 0, 0, 0);

#pragma unroll
        for (int r = 0; r < 4; ++r) {
            float w0 = __expf(e0[r]);
            float w1 = __expf(e1[r]);
            lsum[r] += w0 + w1;
            pw[(4 * g + r) * 40 + cc]      = f2bf(w0);
            pw[(4 * g + r) * 40 + 16 + cc] = f2bf(w1);
        }

        // PV: A = P (row cc, k = 8g..8g+7), B = V^T rows (ct*16+cc)
        bf16x8 apv = *(const bf16x8*)&pw[cc * 40 + g * 8];
#pragma unroll
        for (int ct = 0; ct < 4; ++ct) {
            bf16x8 bv = *(const bf16x8*)&vt_lds[(ct * 16 + cc) * 40 + g * 8];
            acc[ct] = __builtin_amdgcn_mfma_f32_16x16x32_bf16(apv, bv, acc[ct], 0, 0, 0);
        }
    }

    // row-sum reduce across the 16 lanes sharing the same row set
#pragma unroll
    for (int m = 1; m < 16; m <<= 1) {
#pragma unroll
        for (int r = 0; r < 4; ++r)
            lsum[r] += __shfl_xor(lsum[r], m, 64);
    }

    // normalize + stage to LDS for coalesced epilogue
#pragma unroll
    for (int r = 0; r < 4; ++r) {
        const float inv = 1.0f / lsum[r];
#pragma unroll
        for (int ct = 0; ct < 4; ++ct)
            o_lds[(w * 16 + 4 * g + r) * 65 + ct * 16 + cc] = acc[ct][r] * inv;
    }
    __syncthreads();

    // out[b,c,j] = qx[b,c,j] + z ; thread -> (c, 16-j chunk), float4 coalesced
    const int ec = tid >> 2;
    const int ej = (tid & 3) * 16;
    const float* xp = qx  + ((size_t)b * C_ + ec) * N_ + j0 + ej;
    float*       op = out + ((size_t)b * C_ + ec) * N_ + j0 + ej;
#pragma unroll
    for (int q4 = 0; q4 < 4; ++q4) {
        float4 xv = *(const float4*)(xp + q4 * 4);
        float4 zv;
        zv.x = o_lds[(ej + q4 * 4 + 0) * 65 + ec];
        zv.y = o_lds[(ej + q4 * 4 + 1) * 65 + ec];
        zv.z = o_lds[(ej + q4 * 4 + 2) * 65 + ec];
        zv.w = o_lds[(ej + q4 * 4 + 3) * 65 + ec];
        *(float4*)(op + q4 * 4) =
            make_float4(xv.x + zv.x, xv.y + zv.y, xv.z + zv.z, xv.w + zv.w);
    }
}

extern "C" void kernel_launch(void* const* d_in, const int* in_sizes, int n_in,
                              void* d_out, int out_size, void* d_ws, size_t ws_size,
                              hipStream_t stream) {
    const float* qx = (const float*)d_in[0];
    const float* rx = (const float*)d_in[1];
    const float* wq = (const float*)d_in[2];
    const float* bq = (const float*)d_in[3];
    const float* wk = (const float*)d_in[4];
    const float* bk = (const float*)d_in[5];
    const float* wv = (const float*)d_in[6];
    const float* bv = (const float*)d_in[7];
    float* out = (float*)d_out;

    ushort* qb = (ushort*)d_ws;                       // B*N*8
    ushort* kb = qb + (size_t)B_ * N_ * 8;            // B*N*8
    ushort* vb = kb + (size_t)B_ * N_ * 8;            // B*N*64
    ushort* vt = vb + (size_t)B_ * N_ * 64;           // B*64*N

    proj_kernel<<<dim3((B_ * N_) / 256), 256, 0, stream>>>(
        qx, rx, wq, bq, wk, bk, wv, bv, qb, kb, vb);

    transpose_v<<<dim3(N_ / 64, B_), 256, 0, stream>>>(vb, vt);

    attn_kernel<<<dim3(N_ / 64, B_), 256, 0, stream>>>(qb, kb, vt, qx, out);
}

// Round 3
// 154.515 us; speedup vs baseline: 3.5355x; 1.0114x over previous
//
#include <hip/hip_runtime.h>

#define B_ 8
#define C_ 64
#define N_ 4096
#define P_ 8

typedef __attribute__((ext_vector_type(8))) short bf16x8;
typedef __attribute__((ext_vector_type(4))) float f32x4;

static __device__ inline ushort f2bf(float x) {
    union { float f; unsigned u; } c; c.f = x;
    unsigned r = (c.u + 0x7FFFu + ((c.u >> 16) & 1u)) >> 16;   // RNE
    return (ushort)r;
}

static __device__ inline bf16x8 bzero() {
    bf16x8 v;
#pragma unroll
    for (int e = 0; e < 8; ++e) v[e] = 0;
    return v;
}

static __device__ inline int4 pack8(const ushort* s) {
    int4 r;
    r.x = (int)(s[0] | ((unsigned)s[1] << 16));
    r.y = (int)(s[2] | ((unsigned)s[3] << 16));
    r.z = (int)(s[4] | ((unsigned)s[5] << 16));
    r.w = (int)(s[6] | ((unsigned)s[7] << 16));
    return r;
}

// ---------------------------------------------------------------------------
// Kernel A: 1x1-conv projections -> bf16.
//   qb[b,i,p], kb[b,i,p]  (rows are ready-made MFMA fragments, K=8)
//   vb[b,i,c]             (row-major, transposed later)
// ---------------------------------------------------------------------------
__global__ __launch_bounds__(256) void proj_kernel(
    const float* __restrict__ qx, const float* __restrict__ rx,
    const float* __restrict__ wq, const float* __restrict__ bq,
    const float* __restrict__ wk, const float* __restrict__ bk,
    const float* __restrict__ wv, const float* __restrict__ bv,
    ushort* __restrict__ qb, ushort* __restrict__ kb, ushort* __restrict__ vb)
{
    const int gid = blockIdx.x * 256 + threadIdx.x;   // gid = b*N + i
    const int b   = gid >> 12;
    const int i   = gid & (N_ - 1);

    const float* qxp = qx + (size_t)b * C_ * N_ + i;
    const float* rxp = rx + (size_t)b * C_ * N_ + i;

    float accq[P_], acck[P_], accv[C_];
#pragma unroll
    for (int p = 0; p < P_; ++p) { accq[p] = bq[p]; acck[p] = bk[p]; }
#pragma unroll
    for (int o = 0; o < C_; ++o) accv[o] = bv[o];

    for (int c = 0; c < C_; ++c) {
        const float xq = qxp[(size_t)c * N_];
        const float xr = rxp[(size_t)c * N_];
#pragma unroll
        for (int p = 0; p < P_; ++p) {
            accq[p] = fmaf(wq[p * C_ + c], xq, accq[p]);
            acck[p] = fmaf(wk[p * C_ + c], xr, acck[p]);
        }
#pragma unroll
        for (int o = 0; o < C_; ++o)
            accv[o] = fmaf(wv[o * C_ + c], xr, accv[o]);
    }

    ushort q8[8], k8[8], v64[64];
#pragma unroll
    for (int p = 0; p < P_; ++p) { q8[p] = f2bf(accq[p]); k8[p] = f2bf(acck[p]); }
#pragma unroll
    for (int o = 0; o < C_; ++o) v64[o] = f2bf(accv[o]);

    *(int4*)(qb + (size_t)gid * 8) = pack8(q8);
    *(int4*)(kb + (size_t)gid * 8) = pack8(k8);
    int4* vd = (int4*)(vb + (size_t)gid * 64);
#pragma unroll
    for (int o = 0; o < 8; ++o) vd[o] = pack8(&v64[o * 8]);
}

// ---------------------------------------------------------------------------
// Kernel B: V transpose  vb[b,i,c] -> vt[b,c,i]  (bf16), 64x64 tiles via LDS.
// ---------------------------------------------------------------------------
__global__ __launch_bounds__(256) void transpose_v(
    const ushort* __restrict__ vb, ushort* __restrict__ vt)
{
    __shared__ ushort tile[64][72];   // +8 pad
    const int b  = blockIdx.y;
    const int i0 = blockIdx.x * 64;
    const int t  = threadIdx.x;

    {
        const int il = t >> 2, cc = (t & 3) * 16;
        const int4* src = (const int4*)(vb + ((size_t)b * N_ + i0 + il) * 64 + cc);
        *(int4*)&tile[il][cc]     = src[0];
        *(int4*)&tile[il][cc + 8] = src[1];
    }
    __syncthreads();
    {
        const int cl = t >> 2, ic = (t & 3) * 16;
        ushort ov[16];
#pragma unroll
        for (int m = 0; m < 16; ++m) ov[m] = tile[ic + m][cl];
        ushort* dst = vt + ((size_t)b * C_ + cl) * N_ + i0 + ic;
        *(int4*)dst       = pack8(&ov[0]);
        *(int4*)(dst + 8) = pack8(&ov[8]);
    }
}

// ---------------------------------------------------------------------------
// Kernel C: flash attention, bf16 MFMA (16x16x32).
// Block = (b, 64 j-rows) = 4 waves x 16 j. i-tiles of 32.
//  energy: A = K-rows (K-dim p padded 8->32), B = Q rows      -> 2 MFMA
//  P = exp(S) fp32 -> bf16 via per-wave LDS relayout          -> A-frag
//  PV:     A = P, B = V^T tile staged in LDS                  -> 4 MFMA
// No max-subtraction: |energy| <~ 4 (verified round 1).
// ---------------------------------------------------------------------------
__global__ __launch_bounds__(256) void attn_kernel(
    const ushort* __restrict__ qb, const ushort* __restrict__ kb,
    const ushort* __restrict__ vt, const float* __restrict__ qx,
    float* __restrict__ out)
{
    __shared__ ushort vt_lds[64 * 40];     // [c][40] bf16, 32 used + pad
    __shared__ ushort p_lds[4 * 16 * 40];  // per-wave [16][40]
    __shared__ float  o_lds[64 * 65];      // epilogue transpose

    const int tid = threadIdx.x;
    const int w   = tid >> 6;
    const int l   = tid & 63;
    const int cc  = l & 15;
    const int g   = l >> 4;
    const int b   = blockIdx.y;
    const int j0  = blockIdx.x * 64;
    const int jw  = j0 + w * 16;

    // K A-fragment (constant over i): lanes 0-15 hold k-row jw+l, rest zero (pad)
    bf16x8 ak = bzero();
    if (l < 16)
        ak = *(const bf16x8*)(kb + ((size_t)b * N_ + jw + l) * 8);

    f32x4 acc[4];
#pragma unroll
    for (int ct = 0; ct < 4; ++ct) acc[ct] = (f32x4){0.f, 0.f, 0.f, 0.f};
    f32x4 lsum = {0.f, 0.f, 0.f, 0.f};
    const f32x4 zero4 = {0.f, 0.f, 0.f, 0.f};

    // V staging addresses (block-wide): thread -> (c row, 8-elem chunk)
    const int sc  = tid >> 2;
    const int sch = (tid & 3) * 8;
    const ushort* vsrc = vt + ((size_t)b * C_ + sc) * N_ + sch;
    ushort* vdst = &vt_lds[sc * 40 + sch];
    ushort* pw   = &p_lds[w * 640];

    for (int i0 = 0; i0 < N_; i0 += 32) {
        // Q B-fragments (global; lanes 0-15 carry p=0..7, rest zero-pad)
        bf16x8 bq0 = bzero(), bq1 = bzero();
        if (l < 16) {
            bq0 = *(const bf16x8*)(qb + ((size_t)b * N_ + i0 + l) * 8);
            bq1 = *(const bf16x8*)(qb + ((size_t)b * N_ + i0 + 16 + l) * 8);
        }
        __syncthreads();                       // prev tile consumed
        *(int4*)vdst = *(const int4*)(vsrc + i0);
        __syncthreads();                       // tile ready

        // energy S[j, i] : rows jw+4g+r, cols i0+cc (+16)
        f32x4 e0 = __builtin_amdgcn_mfma_f32_16x16x32_bf16(ak, bq0, zero4, 0, 0, 0);
        f32x4 e1 = __builtin_amdgcn_mfma_f32_16x16x32_bf16(ak, bq1, zero4, 0, 0, 0);

#pragma unroll
        for (int r = 0; r < 4; ++r) {
            float w0 = __expf(e0[r]);
            float w1 = __expf(e1[r]);
            lsum[r] += w0 + w1;
            pw[(4 * g + r) * 40 + cc]      = f2bf(w0);
            pw[(4 * g + r) * 40 + 16 + cc] = f2bf(w1);
        }

        // PV: A = P (row cc, k = 8g..8g+7), B = V^T rows (ct*16+cc)
        bf16x8 apv = *(const bf16x8*)&pw[cc * 40 + g * 8];
#pragma unroll
        for (int ct = 0; ct < 4; ++ct) {
            bf16x8 bv = *(const bf16x8*)&vt_lds[(ct * 16 + cc) * 40 + g * 8];
            acc[ct] = __builtin_amdgcn_mfma_f32_16x16x32_bf16(apv, bv, acc[ct], 0, 0, 0);
        }
    }

    // row-sum reduce across the 16 lanes sharing the same row set
#pragma unroll
    for (int m = 1; m < 16; m <<= 1) {
#pragma unroll
        for (int r = 0; r < 4; ++r)
            lsum[r] += __shfl_xor(lsum[r], m, 64);
    }

    // normalize + stage to LDS for coalesced epilogue
#pragma unroll
    for (int r = 0; r < 4; ++r) {
        const float inv = 1.0f / lsum[r];
#pragma unroll
        for (int ct = 0; ct < 4; ++ct)
            o_lds[(w * 16 + 4 * g + r) * 65 + ct * 16 + cc] = acc[ct][r] * inv;
    }
    __syncthreads();

    // out[b,c,j] = qx[b,c,j] + z ; thread -> (c, 16-j chunk), float4 coalesced
    const int ec = tid >> 2;
    const int ej = (tid & 3) * 16;
    const float* xp = qx  + ((size_t)b * C_ + ec) * N_ + j0 + ej;
    float*       op = out + ((size_t)b * C_ + ec) * N_ + j0 + ej;
#pragma unroll
    for (int q4 = 0; q4 < 4; ++q4) {
        float4 xv = *(const float4*)(xp + q4 * 4);
        float4 zv;
        zv.x = o_lds[(ej + q4 * 4 + 0) * 65 + ec];
        zv.y = o_lds[(ej + q4 * 4 + 1) * 65 + ec];
        zv.z = o_lds[(ej + q4 * 4 + 2) * 65 + ec];
        zv.w = o_lds[(ej + q4 * 4 + 3) * 65 + ec];
        *(float4*)(op + q4 * 4) =
            make_float4(xv.x + zv.x, xv.y + zv.y, xv.z + zv.z, xv.w + zv.w);
    }
}

extern "C" void kernel_launch(void* const* d_in, const int* in_sizes, int n_in,
                              void* d_out, int out_size, void* d_ws, size_t ws_size,
                              hipStream_t stream) {
    const float* qx = (const float*)d_in[0];
    const float* rx = (const float*)d_in[1];
    const float* wq = (const float*)d_in[2];
    const float* bq = (const float*)d_in[3];
    const float* wk = (const float*)d_in[4];
    const float* bk = (const float*)d_in[5];
    const float* wv = (const float*)d_in[6];
    const float* bv = (const float*)d_in[7];
    float* out = (float*)d_out;

    ushort* qb = (ushort*)d_ws;                       // B*N*8
    ushort* kb = qb + (size_t)B_ * N_ * 8;            // B*N*8
    ushort* vb = kb + (size_t)B_ * N_ * 8;            // B*N*64
    ushort* vt = vb + (size_t)B_ * N_ * 64;           // B*64*N

    proj_kernel<<<dim3((B_ * N_) / 256), 256, 0, stream>>>(
        qx, rx, wq, bq, wk, bk, wv, bv, qb, kb, vb);

    transpose_v<<<dim3(N_ / 64, B_), 256, 0, stream>>>(vb, vt);

    attn_kernel<<<dim3(N_ / 64, B_), 256, 0, stream>>>(qb, kb, vt, qx, out);
}

// Round 4
// 153.935 us; speedup vs baseline: 3.5488x; 1.0038x over previous
//
#include <hip/hip_runtime.h>

#define B_ 8
#define C_ 64
#define N_ 4096
#define P_ 8

typedef __attribute__((ext_vector_type(8))) short bf16x8;
typedef __attribute__((ext_vector_type(4))) float f32x4;

static __device__ inline ushort f2bf(float x) {
    union { float f; unsigned u; } c; c.f = x;
    unsigned r = (c.u + 0x7FFFu + ((c.u >> 16) & 1u)) >> 16;   // RNE
    return (ushort)r;
}

static __device__ inline bf16x8 bzero() {
    bf16x8 v;
#pragma unroll
    for (int e = 0; e < 8; ++e) v[e] = 0;
    return v;
}

static __device__ inline int4 pack8(const ushort* s) {
    int4 r;
    r.x = (int)(s[0] | ((unsigned)s[1] << 16));
    r.y = (int)(s[2] | ((unsigned)s[3] << 16));
    r.z = (int)(s[4] | ((unsigned)s[5] << 16));
    r.w = (int)(s[6] | ((unsigned)s[7] << 16));
    return r;
}

// ---------------------------------------------------------------------------
// Kernel A: 1x1-conv projections -> bf16.
//   qb[b,i,p], kb[b,i,p]  (rows are ready-made MFMA fragments, K=8)
//   vb[b,i,c]             (row-major, transposed later)
// ---------------------------------------------------------------------------
__global__ __launch_bounds__(256) void proj_kernel(
    const float* __restrict__ qx, const float* __restrict__ rx,
    const float* __restrict__ wq, const float* __restrict__ bq,
    const float* __restrict__ wk, const float* __restrict__ bk,
    const float* __restrict__ wv, const float* __restrict__ bv,
    ushort* __restrict__ qb, ushort* __restrict__ kb, ushort* __restrict__ vb)
{
    const int gid = blockIdx.x * 256 + threadIdx.x;   // gid = b*N + i
    const int b   = gid >> 12;
    const int i   = gid & (N_ - 1);

    const float* qxp = qx + (size_t)b * C_ * N_ + i;
    const float* rxp = rx + (size_t)b * C_ * N_ + i;

    float accq[P_], acck[P_], accv[C_];
#pragma unroll
    for (int p = 0; p < P_; ++p) { accq[p] = bq[p]; acck[p] = bk[p]; }
#pragma unroll
    for (int o = 0; o < C_; ++o) accv[o] = bv[o];

    for (int c = 0; c < C_; ++c) {
        const float xq = qxp[(size_t)c * N_];
        const float xr = rxp[(size_t)c * N_];
#pragma unroll
        for (int p = 0; p < P_; ++p) {
            accq[p] = fmaf(wq[p * C_ + c], xq, accq[p]);
            acck[p] = fmaf(wk[p * C_ + c], xr, acck[p]);
        }
#pragma unroll
        for (int o = 0; o < C_; ++o)
            accv[o] = fmaf(wv[o * C_ + c], xr, accv[o]);
    }

    ushort q8[8], k8[8], v64[64];
#pragma unroll
    for (int p = 0; p < P_; ++p) { q8[p] = f2bf(accq[p]); k8[p] = f2bf(acck[p]); }
#pragma unroll
    for (int o = 0; o < C_; ++o) v64[o] = f2bf(accv[o]);

    *(int4*)(qb + (size_t)gid * 8) = pack8(q8);
    *(int4*)(kb + (size_t)gid * 8) = pack8(k8);
    int4* vd = (int4*)(vb + (size_t)gid * 64);
#pragma unroll
    for (int o = 0; o < 8; ++o) vd[o] = pack8(&v64[o * 8]);
}

// ---------------------------------------------------------------------------
// Kernel B: V transpose  vb[b,i,c] -> vt[b,c,i]  (bf16), 64x64 tiles via LDS.
// ---------------------------------------------------------------------------
__global__ __launch_bounds__(256) void transpose_v(
    const ushort* __restrict__ vb, ushort* __restrict__ vt)
{
    __shared__ ushort tile[64][72];   // +8 pad
    const int b  = blockIdx.y;
    const int i0 = blockIdx.x * 64;
    const int t  = threadIdx.x;

    {
        const int il = t >> 2, cc = (t & 3) * 16;
        const int4* src = (const int4*)(vb + ((size_t)b * N_ + i0 + il) * 64 + cc);
        *(int4*)&tile[il][cc]     = src[0];
        *(int4*)&tile[il][cc + 8] = src[1];
    }
    __syncthreads();
    {
        const int cl = t >> 2, ic = (t & 3) * 16;
        ushort ov[16];
#pragma unroll
        for (int m = 0; m < 16; ++m) ov[m] = tile[ic + m][cl];
        ushort* dst = vt + ((size_t)b * C_ + cl) * N_ + i0 + ic;
        *(int4*)dst       = pack8(&ov[0]);
        *(int4*)(dst + 8) = pack8(&ov[8]);
    }
}

// ---------------------------------------------------------------------------
// Kernel C: flash attention, bf16 MFMA (16x16x32).
// Block = (b, 64 j-rows) = 4 waves x 16 j. i-tiles of 32.
//  energy: A = K-rows (K-dim p padded 8->32), B = Q rows      -> 2 MFMA
//  P = exp(S) fp32 -> bf16 via per-wave LDS relayout          -> A-frag
//  PV:     A = P, B = V^T tile staged in LDS                  -> 4 MFMA
// No max-subtraction: |energy| <~ 4 (verified round 1).
// ---------------------------------------------------------------------------
__global__ __launch_bounds__(256) void attn_kernel(
    const ushort* __restrict__ qb, const ushort* __restrict__ kb,
    const ushort* __restrict__ vt, const float* __restrict__ qx,
    float* __restrict__ out)
{
    __shared__ ushort vt_lds[64 * 40];     // [c][40] bf16, 32 used + pad
    __shared__ ushort p_lds[4 * 16 * 40];  // per-wave [16][40]
    __shared__ float  o_lds[64 * 65];      // epilogue transpose

    const int tid = threadIdx.x;
    const int w   = tid >> 6;
    const int l   = tid & 63;
    const int cc  = l & 15;
    const int g   = l >> 4;
    const int b   = blockIdx.y;
    const int j0  = blockIdx.x * 64;
    const int jw  = j0 + w * 16;

    // K A-fragment (constant over i): lanes 0-15 hold k-row jw+l, rest zero (pad)
    bf16x8 ak = bzero();
    if (l < 16)
        ak = *(const bf16x8*)(kb + ((size_t)b * N_ + jw + l) * 8);

    f32x4 acc[4];
#pragma unroll
    for (int ct = 0; ct < 4; ++ct) acc[ct] = (f32x4){0.f, 0.f, 0.f, 0.f};
    f32x4 lsum = {0.f, 0.f, 0.f, 0.f};
    const f32x4 zero4 = {0.f, 0.f, 0.f, 0.f};

    // V staging addresses (block-wide): thread -> (c row, 8-elem chunk)
    const int sc  = tid >> 2;
    const int sch = (tid & 3) * 8;
    const ushort* vsrc = vt + ((size_t)b * C_ + sc) * N_ + sch;
    ushort* vdst = &vt_lds[sc * 40 + sch];
    ushort* pw   = &p_lds[w * 640];

    for (int i0 = 0; i0 < N_; i0 += 32) {
        // Q B-fragments (global; lanes 0-15 carry p=0..7, rest zero-pad)
        bf16x8 bq0 = bzero(), bq1 = bzero();
        if (l < 16) {
            bq0 = *(const bf16x8*)(qb + ((size_t)b * N_ + i0 + l) * 8);
            bq1 = *(const bf16x8*)(qb + ((size_t)b * N_ + i0 + 16 + l) * 8);
        }
        __syncthreads();                       // prev tile consumed
        *(int4*)vdst = *(const int4*)(vsrc + i0);
        __syncthreads();                       // tile ready

        // energy S[j, i] : rows jw+4g+r, cols i0+cc (+16)
        f32x4 e0 = __builtin_amdgcn_mfma_f32_16x16x32_bf16(ak, bq0, zero4, 0, 0, 0);
        f32x4 e1 = __builtin_amdgcn_mfma_f32_16x16x32_bf16(ak, bq1, zero4, 0, 0, 0);

#pragma unroll
        for (int r = 0; r < 4; ++r) {
            float w0 = __expf(e0[r]);
            float w1 = __expf(e1[r]);
            lsum[r] += w0 + w1;
            pw[(4 * g + r) * 40 + cc]      = f2bf(w0);
            pw[(4 * g + r) * 40 + 16 + cc] = f2bf(w1);
        }

        // PV: A = P (row cc, k = 8g..8g+7), B = V^T rows (ct*16+cc)
        bf16x8 apv = *(const bf16x8*)&pw[cc * 40 + g * 8];
#pragma unroll
        for (int ct = 0; ct < 4; ++ct) {
            bf16x8 bv = *(const bf16x8*)&vt_lds[(ct * 16 + cc) * 40 + g * 8];
            acc[ct] = __builtin_amdgcn_mfma_f32_16x16x32_bf16(apv, bv, acc[ct], 0, 0, 0);
        }
    }

    // row-sum reduce across the 16 lanes sharing the same row set
#pragma unroll
    for (int m = 1; m < 16; m <<= 1) {
#pragma unroll
        for (int r = 0; r < 4; ++r)
            lsum[r] += __shfl_xor(lsum[r], m, 64);
    }

    // normalize + stage to LDS for coalesced epilogue
#pragma unroll
    for (int r = 0; r < 4; ++r) {
        const float inv = 1.0f / lsum[r];
#pragma unroll
        for (int ct = 0; ct < 4; ++ct)
            o_lds[(w * 16 + 4 * g + r) * 65 + ct * 16 + cc] = acc[ct][r] * inv;
    }
    __syncthreads();

    // out[b,c,j] = qx[b,c,j] + z ; thread -> (c, 16-j chunk), float4 coalesced
    const int ec = tid >> 2;
    const int ej = (tid & 3) * 16;
    const float* xp = qx  + ((size_t)b * C_ + ec) * N_ + j0 + ej;
    float*       op = out + ((size_t)b * C_ + ec) * N_ + j0 + ej;
#pragma unroll
    for (int q4 = 0; q4 < 4; ++q4) {
        float4 xv = *(const float4*)(xp + q4 * 4);
        float4 zv;
        zv.x = o_lds[(ej + q4 * 4 + 0) * 65 + ec];
        zv.y = o_lds[(ej + q4 * 4 + 1) * 65 + ec];
        zv.z = o_lds[(ej + q4 * 4 + 2) * 65 + ec];
        zv.w = o_lds[(ej + q4 * 4 + 3) * 65 + ec];
        *(float4*)(op + q4 * 4) =
            make_float4(xv.x + zv.x, xv.y + zv.y, xv.z + zv.z, xv.w + zv.w);
    }
}

extern "C" void kernel_launch(void* const* d_in, const int* in_sizes, int n_in,
                              void* d_out, int out_size, void* d_ws, size_t ws_size,
                              hipStream_t stream) {
    const float* qx = (const float*)d_in[0];
    const float* rx = (const float*)d_in[1];
    const float* wq = (const float*)d_in[2];
    const float* bq = (const float*)d_in[3];
    const float* wk = (const float*)d_in[4];
    const float* bk = (const float*)d_in[5];
    const float* wv = (const float*)d_in[6];
    const float* bv = (const float*)d_in[7];
    float* out = (float*)d_out;

    ushort* qb = (ushort*)d_ws;                       // B*N*8
    ushort* kb = qb + (size_t)B_ * N_ * 8;            // B*N*8
    ushort* vb = kb + (size_t)B_ * N_ * 8;            // B*N*64
    ushort* vt = vb + (size_t)B_ * N_ * 64;           // B*64*N

    proj_kernel<<<dim3((B_ * N_) / 256), 256, 0, stream>>>(
        qx, rx, wq, bq, wk, bk, wv, bv, qb, kb, vb);

    transpose_v<<<dim3(N_ / 64, B_), 256, 0, stream>>>(vb, vt);

    attn_kernel<<<dim3(N_ / 64, B_), 256, 0, stream>>>(qb, kb, vt, qx, out);
}